// Round 2
// baseline (1201.547 us; speedup 1.0000x reference)
//
#include <hip/hip_runtime.h>
#include <hip/hip_bf16.h>
#include <cmath>

#define CCH 512
#define TLEN 8192
#define NB 8
#define KFILT 12

typedef unsigned short u16;
typedef __attribute__((ext_vector_type(8))) short short8;
typedef __attribute__((ext_vector_type(8))) unsigned short ushort8;
typedef __attribute__((ext_vector_type(4))) float float4v;
typedef __attribute__((ext_vector_type(4))) int int4v;

struct Filt { float f[KFILT]; };

// ---------- host: kaiser-sinc filter (double precision, matches numpy) ----------
static double bessel_i0(double x) {
    double sum = 1.0, term = 1.0;
    for (int k = 1; k < 40; ++k) {
        double t = (x * 0.5) / k;
        term *= t * t;
        sum += term;
        if (term < 1e-18 * sum) break;
    }
    return sum;
}

static void make_filter(float* out) {
    const int ksize = KFILT, half = KFILT / 2;
    const double cutoff = 0.5 / 2.0;
    const double half_width = 0.6 / 2.0;
    const double delta_f = 4.0 * half_width;
    const double PI = 3.14159265358979323846;
    double A = 2.285 * (half - 1) * PI * delta_f + 7.95;
    double beta;
    if (A > 50.0) beta = 0.1102 * (A - 8.7);
    else if (A >= 21.0) beta = 0.5842 * pow(A - 21.0, 0.4) + 0.07886 * (A - 21.0);
    else beta = 0.0;
    double i0b = bessel_i0(beta);
    double sum = 0.0, f[KFILT];
    for (int n = 0; n < ksize; ++n) {
        double r = (2.0 * n) / (ksize - 1) - 1.0;
        double w = bessel_i0(beta * sqrt(fmax(0.0, 1.0 - r * r))) / i0b;
        double t = (n - half) + 0.5;
        double xx = 2.0 * cutoff * t;
        double snc = (xx == 0.0) ? 1.0 : sin(PI * xx) / (PI * xx);
        f[n] = 2.0 * cutoff * w * snc;
        sum += f[n];
    }
    for (int n = 0; n < ksize; ++n) out[n] = (float)(f[n] / sum);
}

// ---------- device helpers ----------
__device__ __forceinline__ float bf2f(u16 u) {
    return __uint_as_float(((unsigned int)u) << 16);
}
__device__ __forceinline__ u16 f2bf(float f) {
    unsigned int x = __float_as_uint(f);
    unsigned int r = (x + 0x7fffu + ((x >> 16) & 1u)) >> 16;
    return (u16)r;
}
__device__ __forceinline__ float ldin(const void* p, size_t i, int isf) {
    return isf ? ((const float*)p)[i] : bf2f(((const u16*)p)[i]);
}
__device__ __forceinline__ void gl_lds16(const void* g, void* s) {
    __builtin_amdgcn_global_load_lds(
        (const __attribute__((address_space(1))) unsigned int*)g,
        (__attribute__((address_space(3))) unsigned int*)s, 16, 0, 0);
}

// ---------- dtype sniffer: bf16-view of f32 data has wild exponents ----------
__global__ __launch_bounds__(256) void k_detect(const u16* __restrict__ x,
                                                int* __restrict__ flag) {
    int tid = threadIdx.x;
    int bad = 0;
    for (int i = tid; i < 4096; i += 256) {
        int e = (x[i] >> 7) & 0xFF;
        if (e >= 0x86) bad++;   // |v| >= 64 or inf/nan as bf16
    }
    for (int off = 32; off > 0; off >>= 1) bad += __shfl_down(bad, off, 64);
    __shared__ int r[4];
    if ((tid & 63) == 0) r[tid >> 6] = bad;
    __syncthreads();
    if (tid == 0) flag[0] = (r[0] + r[1] + r[2] + r[3] >= 64) ? 1 : 0;
}

// ---------- per-out-channel weight-norm scale: g / ||v|| ----------
__global__ __launch_bounds__(256) void k_scales(const void* __restrict__ v,
                                                const void* __restrict__ g,
                                                float* __restrict__ scales,
                                                const int* __restrict__ flg) {
    int isf = *flg;
    int blk = blockIdx.x;            // [0, 3*512)
    int tid = threadIdx.x;
    float s = 0.f;
    for (int i = tid; i < CCH * 3; i += 256) {
        float x = ldin(v, (size_t)blk * (CCH * 3) + i, isf);
        s = fmaf(x, x, s);
    }
    for (int off = 32; off > 0; off >>= 1) s += __shfl_down(s, off, 64);
    __shared__ float red[4];
    if ((tid & 63) == 0) red[tid >> 6] = s;
    __syncthreads();
    if (tid == 0) {
        float tot = red[0] + red[1] + red[2] + red[3];
        scales[blk] = ldin(g, blk, isf) / sqrtf(tot);
    }
}

// ---------- repack weights: Wp[l][tap][co][ci] = v[l][co][ci][tap] (bf16) ----------
__global__ __launch_bounds__(256) void k_repack(const void* __restrict__ v,
                                                u16* __restrict__ wp,
                                                const int* __restrict__ flg) {
    int isf = *flg;
    int l = blockIdx.y;
    int i = blockIdx.x * 256 + threadIdx.x;   // < 3*512*512
    int tap = i >> 18;
    int rem = i & 262143;
    int co = rem >> 9, ci = rem & 511;
    size_t src = (((size_t)l * CCH + co) * CCH + ci) * 3 + tap;
    u16 val = isf ? f2bf(((const float*)v)[src]) : ((const u16*)v)[src];
    wp[(((size_t)l * 3 + tap) * CCH + co) * CCH + ci] = val;
}

// ---------- upsample+snake value generator, all indices compile-time ----------
template<int UL>
__device__ __forceinline__ float su_val(const float* xr, const Filt& F,
                                        float a, float invb) {
    constexpr int S = (UL < 0) ? -(((-UL) + 1) / 2) : (UL / 2);   // floor(UL/2)
    constexpr int P = ((UL % 2) + 2) % 2;                          // parity
    constexpr int B = S + (P ? 4 : 3);                             // xr base idx
    float acc = F.f[P] * xr[B];
    #pragma unroll
    for (int r = 1; r < 6; ++r) acc = fmaf(F.f[2 * r + P], xr[B + r], acc);
    acc *= 2.0f;
    float sn = __sinf(acc * a);
    return fmaf(invb, sn * sn, acc);
}

// ---------- fused activation1d: all-register streaming (zero LDS) ----------
__global__ __launch_bounds__(256) void k_act(const void* __restrict__ xsrc,
                                             const void* __restrict__ alpha,
                                             const void* __restrict__ beta,
                                             int prmofs, u16* __restrict__ xt,
                                             Filt F, const int* __restrict__ flg,
                                             int layer0) {
    const int isf = *flg;
    const int sif = layer0 ? isf : 0;   // carrier is always bf16 after layer 0
    const int tid = threadIdx.x;
    const int lane = tid & 63, w = tid >> 6;
    const int b = blockIdx.z;
    const int c = blockIdx.y * 64 + lane;
    const int t0 = blockIdx.x * 128 + w * 32;        // wave-uniform
    const size_t rowbase = ((size_t)(b * CCH + c)) * TLEN;

    const float a = expf(ldin(alpha, prmofs + c, isf));
    const float invb = 1.0f / (expf(ldin(beta, prmofs + c, isf)) + 1e-9f);

    // ---- x window: xr[k] = x[clamp(t0-6+k)], k in [0,44) ----
    float xr[44];
    const bool interior = (t0 != 0) && (t0 != TLEN - 32);   // wave-uniform
    if (sif) {
        const float* xp = (const float*)xsrc + rowbase;
        if (interior) {
            #pragma unroll
            for (int i = 0; i < 12; ++i) {
                float4v v = *(const float4v*)(xp + t0 - 8 + i * 4);
                #pragma unroll
                for (int j = 0; j < 4; ++j) {
                    int k = i * 4 + j - 2;
                    if (k >= 0 && k < 44) xr[k] = v[j];
                }
            }
        } else {
            #pragma unroll
            for (int k = 0; k < 44; ++k)
                xr[k] = xp[min(max(t0 - 6 + k, 0), TLEN - 1)];
        }
    } else {
        const u16* xp = (const u16*)xsrc + rowbase;
        if (interior) {
            #pragma unroll
            for (int i = 0; i < 6; ++i) {
                ushort8 v = *(const ushort8*)(xp + t0 - 8 + i * 8);
                #pragma unroll
                for (int j = 0; j < 8; ++j) {
                    int k = i * 8 + j - 2;
                    if (k >= 0 && k < 44) xr[k] = bf2f(v[j]);
                }
            }
        } else {
            #pragma unroll
            for (int k = 0; k < 44; ++k)
                xr[k] = bf2f(xp[min(max(t0 - 6 + k, 0), TLEN - 1)]);
        }
    }

    // ---- init rolling window: slots for u_local = -5..6, slot(u) = u mod 12 ----
    float wv[12];
    wv[7]  = su_val<-5>(xr, F, a, invb);
    wv[8]  = su_val<-4>(xr, F, a, invb);
    wv[9]  = su_val<-3>(xr, F, a, invb);
    wv[10] = su_val<-2>(xr, F, a, invb);
    wv[11] = su_val<-1>(xr, F, a, invb);
    wv[0]  = su_val<0>(xr, F, a, invb);
    wv[1]  = su_val<1>(xr, F, a, invb);
    wv[2]  = su_val<2>(xr, F, a, invb);
    wv[3]  = su_val<3>(xr, F, a, invb);
    wv[4]  = su_val<4>(xr, F, a, invb);
    wv[5]  = su_val<5>(xr, F, a, invb);
    wv[6]  = su_val<6>(xr, F, a, invb);
    // left edge: u<0 clamps to u=0 (edge-replicate of snake output)
    if (t0 == 0) { wv[7] = wv[8] = wv[9] = wv[10] = wv[11] = wv[0]; }
    // right edge: u>2T-1 clamps to u=2T-1 (odd, u_local=63 at the last thread)
    const bool right = (t0 == TLEN - 32);
    const float su_hi = su_val<63>(xr, F, a, invb);

    u16* orow = xt + (size_t)b * TLEN * CCH + c;

#define IDXW(u) ((((u) % 12) + 12) % 12)
#define ACT_STEP(TL) { \
      float acc = F.f[0] * wv[IDXW(2*(TL)-5)]; \
      acc = fmaf(F.f[1],  wv[IDXW(2*(TL)-4)], acc); \
      acc = fmaf(F.f[2],  wv[IDXW(2*(TL)-3)], acc); \
      acc = fmaf(F.f[3],  wv[IDXW(2*(TL)-2)], acc); \
      acc = fmaf(F.f[4],  wv[IDXW(2*(TL)-1)], acc); \
      acc = fmaf(F.f[5],  wv[IDXW(2*(TL)+0)], acc); \
      acc = fmaf(F.f[6],  wv[IDXW(2*(TL)+1)], acc); \
      acc = fmaf(F.f[7],  wv[IDXW(2*(TL)+2)], acc); \
      acc = fmaf(F.f[8],  wv[IDXW(2*(TL)+3)], acc); \
      acc = fmaf(F.f[9],  wv[IDXW(2*(TL)+4)], acc); \
      acc = fmaf(F.f[10], wv[IDXW(2*(TL)+5)], acc); \
      acc = fmaf(F.f[11], wv[IDXW(2*(TL)+6)], acc); \
      orow[(size_t)(t0 + (TL)) * CCH] = f2bf(acc); \
      if ((TL) < 31) { \
        float nv1 = su_val<2*(TL)+7>(xr, F, a, invb); \
        float nv2 = su_val<2*(TL)+8>(xr, F, a, invb); \
        if ((2*(TL)+7) > 63) nv1 = right ? su_hi : nv1; \
        if ((2*(TL)+8) > 63) nv2 = right ? su_hi : nv2; \
        wv[IDXW(2*(TL)+7)] = nv1; \
        wv[IDXW(2*(TL)+8)] = nv2; \
      } \
    }

    ACT_STEP(0)  ACT_STEP(1)  ACT_STEP(2)  ACT_STEP(3)
    ACT_STEP(4)  ACT_STEP(5)  ACT_STEP(6)  ACT_STEP(7)
    ACT_STEP(8)  ACT_STEP(9)  ACT_STEP(10) ACT_STEP(11)
    ACT_STEP(12) ACT_STEP(13) ACT_STEP(14) ACT_STEP(15)
    ACT_STEP(16) ACT_STEP(17) ACT_STEP(18) ACT_STEP(19)
    ACT_STEP(20) ACT_STEP(21) ACT_STEP(22) ACT_STEP(23)
    ACT_STEP(24) ACT_STEP(25) ACT_STEP(26) ACT_STEP(27)
    ACT_STEP(28) ACT_STEP(29) ACT_STEP(30) ACT_STEP(31)
#undef ACT_STEP
#undef IDXW
}

// ---------- wn_conv (k=3 dilated) as MFMA implicit GEMM + residual ----------
// Round-2 restructure: A (weights) is NO LONGER staged in LDS. Each A-fragment
// is a contiguous 16B global load (lane l15 -> co row, q -> ci sub-block):
// 16 rows x 64B lines per wave-instr, 2-way wave reuse + cross-block reuse via
// L1 (24.6KB/step < 32KB L1). LDS holds only the X dbuf (2x12288B static) ->
// occupancy limit moves from LDS (2 blocks/CU) to VGPR; __launch_bounds__(256,4)
// targets 4 blocks/CU = 16 waves. The per-step barrier now guards only 3
// gl_lds/wave, issued a full compute-phase ahead; A loads are barrier-free and
// compiler-pipelined across steps via plain vmcnt counting.
__global__ __launch_bounds__(256, 4) void k_conv(const u16* __restrict__ xt,
                                              const u16* __restrict__ wp,
                                              const float* __restrict__ scales,
                                              const void* __restrict__ bias,
                                              int bofs,
                                              const void* __restrict__ rsrc,
                                              int layer0,
                                              u16* __restrict__ wdst,
                                              void* __restrict__ outp, int d,
                                              const int* __restrict__ flg) {
    __shared__ __align__(16) char Xsm[2][12288];
    const int isf = *flg;
    const int rif = layer0 ? isf : 0;
    const int tid = threadIdx.x;
    const int lane = tid & 63, wid = tid >> 6;
    const int wm = wid & 1, wn = wid >> 1;
    const int b = blockIdx.z, co0 = blockIdx.y * 128, t0 = blockIdx.x * 128;
    const int q = lane >> 4, l15 = lane & 15;
    const int nX = (128 + 2 * d) * 4;              // live X granules
    const bool edge = (t0 == 0) || (t0 + 128 == TLEN);
    const u16* xtb = xt + (size_t)b * TLEN * CCH;

    // per-lane A base: row co0 + wm*64 + l15, k-offset q*8 (elements)
    // strides (elements): tap 262144, mi 8192, ci-step 32
    const u16* wbase = wp + ((size_t)(co0 + wm * 64 + l15)) * CCH + q * 8;

    // per-lane X staging source rows (step-invariant; ci0 added per step)
    const u16* xsrc3[3];
    #pragma unroll
    for (int i = 0; i < 3; ++i) {
        int L = (i * 4 + wid) * 64 + lane;
        int t = L >> 2;
        int g = (L & 3) ^ ((t >> 1) & 3);
        int tg = min(max(t0 - d + t, 0), TLEN - 1);
        xsrc3[i] = xtb + (size_t)tg * CCH + g * 8;
    }

    float4v acc[4][4];
    #pragma unroll
    for (int i = 0; i < 4; ++i)
        #pragma unroll
        for (int j = 0; j < 4; ++j) acc[i][j] = (float4v){0.f, 0.f, 0.f, 0.f};

    auto stageX = [&](int ci0, char* Xs) {
        #pragma unroll
        for (int i = 0; i < 3; ++i)
            gl_lds16(xsrc3[i] + ci0, Xs + (i * 4 + wid) * 64 * 16);
    };
    auto fixX = [&](char* Xs) {   // zero out-of-range rows (conv zero-pad)
        for (int j = tid; j < nX; j += 256) {
            int tg = t0 - d + (j >> 2);
            if (tg < 0 || tg >= TLEN)
                *(int4v*)(Xs + (size_t)j * 16) = (int4v){0, 0, 0, 0};
        }
    };

    // ---- prologue: stage step 0 ----
    stageX(0, Xsm[0]);
    __syncthreads();                       // vmcnt(0) drain + barrier
    if (edge) { fixX(Xsm[0]); __syncthreads(); }

    // ---- main loop: prefetch X(s+1) || A direct loads + MFMA on s ----
    #pragma unroll 2
    for (int s = 0; s < 16; ++s) {
        const int cur = s & 1;
        const char* Xs = Xsm[cur];
        if (s < 15) stageX((s + 1) * 32, Xsm[cur ^ 1]);
        #pragma unroll
        for (int tap = 0; tap < 3; ++tap) {
            short8 af[4], bfr[4];
            #pragma unroll
            for (int mi = 0; mi < 4; ++mi)
                af[mi] = *(const short8*)(wbase + (size_t)tap * 262144 +
                                          mi * 8192 + s * 32);
            #pragma unroll
            for (int ni = 0; ni < 4; ++ni) {
                int r = wn * 64 + ni * 16 + l15 + tap * d;
                bfr[ni] = *(const short8*)(Xs + r * 64 + ((q ^ ((r >> 1) & 3)) * 16));
            }
            #pragma unroll
            for (int mi = 0; mi < 4; ++mi)
                #pragma unroll
                for (int ni = 0; ni < 4; ++ni)
                    acc[mi][ni] = __builtin_amdgcn_mfma_f32_16x16x32_bf16(
                        af[mi], bfr[ni], acc[mi][ni], 0, 0, 0);
        }
        __syncthreads();                   // drains X prefetch + WAR guard
        if (edge && s < 15) {
            fixX(Xsm[cur ^ 1]);
            __syncthreads();
        }
    }

    // ---- epilogue: y = scale*acc + bias + residual ----
    float scl[4][4], bia[4][4];
    #pragma unroll
    for (int mi = 0; mi < 4; ++mi)
        #pragma unroll
        for (int rg = 0; rg < 4; ++rg) {
            int co = co0 + wm * 64 + mi * 16 + q * 4 + rg;
            scl[mi][rg] = scales[co];
            bia[mi][rg] = ldin(bias, bofs + co, isf);
        }
    #pragma unroll
    for (int mi = 0; mi < 4; ++mi)
        #pragma unroll
        for (int ni = 0; ni < 4; ++ni) {
            int tg = t0 + wn * 64 + ni * 16 + l15;
            #pragma unroll
            for (int rg = 0; rg < 4; ++rg) {
                int co = co0 + wm * 64 + mi * 16 + q * 4 + rg;
                size_t idx = ((size_t)(b * CCH + co)) * TLEN + tg;
                float resid = rif ? ((const float*)rsrc)[idx]
                                  : bf2f(((const u16*)rsrc)[idx]);
                float val = fmaf(acc[mi][ni][rg], scl[mi][rg], bia[mi][rg]) + resid;
                if (wdst) {
                    wdst[idx] = f2bf(val);
                } else {
                    if (isf) ((float*)outp)[idx] = val;
                    else ((u16*)outp)[idx] = f2bf(val);
                }
            }
        }
}

// ---------- launcher ----------
extern "C" void kernel_launch(void* const* d_in, const int* in_sizes, int n_in,
                              void* d_out, int out_size, void* d_ws, size_t ws_size,
                              hipStream_t stream) {
    const void* x_in  = d_in[0];
    const void* v_in  = d_in[1];
    const void* g_in  = d_in[2];
    const void* b_in  = d_in[3];
    const void* al_in = d_in[4];
    const void* be_in = d_in[5];

    char* ws = (char*)d_ws;
    u16*   xc     = (u16*)ws;                                     // 67108864 B
    u16*   xt     = (u16*)(ws + 67108864);                        // 67108864 B
    u16*   wp     = (u16*)(ws + 134217728);                       // 4718592 B
    float* scales = (float*)(ws + 134217728 + 4718592);           // 6144 B
    int*   flag   = (int*)(ws + 134217728 + 4718592 + 6144);

    Filt F;
    make_filter(F.f);

    k_detect<<<1, 256, 0, stream>>>((const u16*)x_in, flag);
    k_scales<<<3 * CCH, 256, 0, stream>>>(v_in, g_in, scales, flag);
    k_repack<<<dim3(3072, 3), 256, 0, stream>>>(v_in, wp, flag);

    const int dil[3] = {1, 3, 5};
    for (int l = 0; l < 3; ++l) {
        const void* src = (l == 0) ? x_in : (const void*)xc;
        k_act<<<dim3(TLEN / 128, CCH / 64, NB), 256, 0, stream>>>(
            src, al_in, be_in, l * CCH, xt, F, flag, (l == 0) ? 1 : 0);
        k_conv<<<dim3(TLEN / 128, CCH / 128, NB), 256, 0, stream>>>(
            xt, wp + (size_t)l * 3 * CCH * CCH, scales + l * CCH, b_in, l * CCH,
            src, (l == 0) ? 1 : 0,
            (l == 2) ? (u16*)nullptr : xc,
            (l == 2) ? d_out : nullptr, dil[l], flag);
    }
}

// Round 3
// 1116.625 us; speedup vs baseline: 1.0761x; 1.0761x over previous
//
#include <hip/hip_runtime.h>
#include <hip/hip_bf16.h>
#include <cmath>

#define CCH 512
#define TLEN 8192
#define NB 8
#define KFILT 12

typedef unsigned short u16;
typedef __attribute__((ext_vector_type(8))) short short8;
typedef __attribute__((ext_vector_type(8))) unsigned short ushort8;
typedef __attribute__((ext_vector_type(4))) float float4v;
typedef __attribute__((ext_vector_type(4))) int int4v;

struct Filt { float f[KFILT]; };

// ---------- host: kaiser-sinc filter (double precision, matches numpy) ----------
static double bessel_i0(double x) {
    double sum = 1.0, term = 1.0;
    for (int k = 1; k < 40; ++k) {
        double t = (x * 0.5) / k;
        term *= t * t;
        sum += term;
        if (term < 1e-18 * sum) break;
    }
    return sum;
}

static void make_filter(float* out) {
    const int ksize = KFILT, half = KFILT / 2;
    const double cutoff = 0.5 / 2.0;
    const double half_width = 0.6 / 2.0;
    const double delta_f = 4.0 * half_width;
    const double PI = 3.14159265358979323846;
    double A = 2.285 * (half - 1) * PI * delta_f + 7.95;
    double beta;
    if (A > 50.0) beta = 0.1102 * (A - 8.7);
    else if (A >= 21.0) beta = 0.5842 * pow(A - 21.0, 0.4) + 0.07886 * (A - 21.0);
    else beta = 0.0;
    double i0b = bessel_i0(beta);
    double sum = 0.0, f[KFILT];
    for (int n = 0; n < ksize; ++n) {
        double r = (2.0 * n) / (ksize - 1) - 1.0;
        double w = bessel_i0(beta * sqrt(fmax(0.0, 1.0 - r * r))) / i0b;
        double t = (n - half) + 0.5;
        double xx = 2.0 * cutoff * t;
        double snc = (xx == 0.0) ? 1.0 : sin(PI * xx) / (PI * xx);
        f[n] = 2.0 * cutoff * w * snc;
        sum += f[n];
    }
    for (int n = 0; n < ksize; ++n) out[n] = (float)(f[n] / sum);
}

// ---------- device helpers ----------
__device__ __forceinline__ float bf2f(u16 u) {
    return __uint_as_float(((unsigned int)u) << 16);
}
__device__ __forceinline__ u16 f2bf(float f) {
    unsigned int x = __float_as_uint(f);
    unsigned int r = (x + 0x7fffu + ((x >> 16) & 1u)) >> 16;
    return (u16)r;
}
__device__ __forceinline__ float ldin(const void* p, size_t i, int isf) {
    return isf ? ((const float*)p)[i] : bf2f(((const u16*)p)[i]);
}
__device__ __forceinline__ void gl_lds16(const void* g, void* s) {
    __builtin_amdgcn_global_load_lds(
        (const __attribute__((address_space(1))) unsigned int*)g,
        (__attribute__((address_space(3))) unsigned int*)s, 16, 0, 0);
}

// ---------- dtype sniffer: bf16-view of f32 data has wild exponents ----------
__global__ __launch_bounds__(256) void k_detect(const u16* __restrict__ x,
                                                int* __restrict__ flag) {
    int tid = threadIdx.x;
    int bad = 0;
    for (int i = tid; i < 4096; i += 256) {
        int e = (x[i] >> 7) & 0xFF;
        if (e >= 0x86) bad++;   // |v| >= 64 or inf/nan as bf16
    }
    for (int off = 32; off > 0; off >>= 1) bad += __shfl_down(bad, off, 64);
    __shared__ int r[4];
    if ((tid & 63) == 0) r[tid >> 6] = bad;
    __syncthreads();
    if (tid == 0) flag[0] = (r[0] + r[1] + r[2] + r[3] >= 64) ? 1 : 0;
}

// ---------- per-out-channel weight-norm scale: g / ||v|| ----------
__global__ __launch_bounds__(256) void k_scales(const void* __restrict__ v,
                                                const void* __restrict__ g,
                                                float* __restrict__ scales,
                                                const int* __restrict__ flg) {
    int isf = *flg;
    int blk = blockIdx.x;            // [0, 3*512)
    int tid = threadIdx.x;
    float s = 0.f;
    for (int i = tid; i < CCH * 3; i += 256) {
        float x = ldin(v, (size_t)blk * (CCH * 3) + i, isf);
        s = fmaf(x, x, s);
    }
    for (int off = 32; off > 0; off >>= 1) s += __shfl_down(s, off, 64);
    __shared__ float red[4];
    if ((tid & 63) == 0) red[tid >> 6] = s;
    __syncthreads();
    if (tid == 0) {
        float tot = red[0] + red[1] + red[2] + red[3];
        scales[blk] = ldin(g, blk, isf) / sqrtf(tot);
    }
}

// ---------- repack weights: Wp[l][tap][co][ci] = v[l][co][ci][tap] (bf16) ----------
__global__ __launch_bounds__(256) void k_repack(const void* __restrict__ v,
                                                u16* __restrict__ wp,
                                                const int* __restrict__ flg) {
    int isf = *flg;
    int l = blockIdx.y;
    int i = blockIdx.x * 256 + threadIdx.x;   // < 3*512*512
    int tap = i >> 18;
    int rem = i & 262143;
    int co = rem >> 9, ci = rem & 511;
    size_t src = (((size_t)l * CCH + co) * CCH + ci) * 3 + tap;
    u16 val = isf ? f2bf(((const float*)v)[src]) : ((const u16*)v)[src];
    wp[(((size_t)l * 3 + tap) * CCH + co) * CCH + ci] = val;
}

// ---------- upsample+snake value generator, all indices compile-time ----------
template<int UL>
__device__ __forceinline__ float su_val(const float* xr, const Filt& F,
                                        float a, float invb) {
    constexpr int S = (UL < 0) ? -(((-UL) + 1) / 2) : (UL / 2);   // floor(UL/2)
    constexpr int P = ((UL % 2) + 2) % 2;                          // parity
    constexpr int B = S + (P ? 4 : 3);                             // xr base idx
    float acc = F.f[P] * xr[B];
    #pragma unroll
    for (int r = 1; r < 6; ++r) acc = fmaf(F.f[2 * r + P], xr[B + r], acc);
    acc *= 2.0f;
    float sn = __sinf(acc * a);
    return fmaf(invb, sn * sn, acc);
}

// ---------- fused activation1d: all-register streaming (zero LDS) ----------
__global__ __launch_bounds__(256) void k_act(const void* __restrict__ xsrc,
                                             const void* __restrict__ alpha,
                                             const void* __restrict__ beta,
                                             int prmofs, u16* __restrict__ xt,
                                             Filt F, const int* __restrict__ flg,
                                             int layer0) {
    const int isf = *flg;
    const int sif = layer0 ? isf : 0;   // carrier is always bf16 after layer 0
    const int tid = threadIdx.x;
    const int lane = tid & 63, w = tid >> 6;
    const int b = blockIdx.z;
    const int c = blockIdx.y * 64 + lane;
    const int t0 = blockIdx.x * 128 + w * 32;        // wave-uniform
    const size_t rowbase = ((size_t)(b * CCH + c)) * TLEN;

    const float a = expf(ldin(alpha, prmofs + c, isf));
    const float invb = 1.0f / (expf(ldin(beta, prmofs + c, isf)) + 1e-9f);

    // ---- x window: xr[k] = x[clamp(t0-6+k)], k in [0,44) ----
    float xr[44];
    const bool interior = (t0 != 0) && (t0 != TLEN - 32);   // wave-uniform
    if (sif) {
        const float* xp = (const float*)xsrc + rowbase;
        if (interior) {
            #pragma unroll
            for (int i = 0; i < 12; ++i) {
                float4v v = *(const float4v*)(xp + t0 - 8 + i * 4);
                #pragma unroll
                for (int j = 0; j < 4; ++j) {
                    int k = i * 4 + j - 2;
                    if (k >= 0 && k < 44) xr[k] = v[j];
                }
            }
        } else {
            #pragma unroll
            for (int k = 0; k < 44; ++k)
                xr[k] = xp[min(max(t0 - 6 + k, 0), TLEN - 1)];
        }
    } else {
        const u16* xp = (const u16*)xsrc + rowbase;
        if (interior) {
            #pragma unroll
            for (int i = 0; i < 6; ++i) {
                ushort8 v = *(const ushort8*)(xp + t0 - 8 + i * 8);
                #pragma unroll
                for (int j = 0; j < 8; ++j) {
                    int k = i * 8 + j - 2;
                    if (k >= 0 && k < 44) xr[k] = bf2f(v[j]);
                }
            }
        } else {
            #pragma unroll
            for (int k = 0; k < 44; ++k)
                xr[k] = bf2f(xp[min(max(t0 - 6 + k, 0), TLEN - 1)]);
        }
    }

    // ---- init rolling window: slots for u_local = -5..6, slot(u) = u mod 12 ----
    float wv[12];
    wv[7]  = su_val<-5>(xr, F, a, invb);
    wv[8]  = su_val<-4>(xr, F, a, invb);
    wv[9]  = su_val<-3>(xr, F, a, invb);
    wv[10] = su_val<-2>(xr, F, a, invb);
    wv[11] = su_val<-1>(xr, F, a, invb);
    wv[0]  = su_val<0>(xr, F, a, invb);
    wv[1]  = su_val<1>(xr, F, a, invb);
    wv[2]  = su_val<2>(xr, F, a, invb);
    wv[3]  = su_val<3>(xr, F, a, invb);
    wv[4]  = su_val<4>(xr, F, a, invb);
    wv[5]  = su_val<5>(xr, F, a, invb);
    wv[6]  = su_val<6>(xr, F, a, invb);
    // left edge: u<0 clamps to u=0 (edge-replicate of snake output)
    if (t0 == 0) { wv[7] = wv[8] = wv[9] = wv[10] = wv[11] = wv[0]; }
    // right edge: u>2T-1 clamps to u=2T-1 (odd, u_local=63 at the last thread)
    const bool right = (t0 == TLEN - 32);
    const float su_hi = su_val<63>(xr, F, a, invb);

    u16* orow = xt + (size_t)b * TLEN * CCH + c;

#define IDXW(u) ((((u) % 12) + 12) % 12)
#define ACT_STEP(TL) { \
      float acc = F.f[0] * wv[IDXW(2*(TL)-5)]; \
      acc = fmaf(F.f[1],  wv[IDXW(2*(TL)-4)], acc); \
      acc = fmaf(F.f[2],  wv[IDXW(2*(TL)-3)], acc); \
      acc = fmaf(F.f[3],  wv[IDXW(2*(TL)-2)], acc); \
      acc = fmaf(F.f[4],  wv[IDXW(2*(TL)-1)], acc); \
      acc = fmaf(F.f[5],  wv[IDXW(2*(TL)+0)], acc); \
      acc = fmaf(F.f[6],  wv[IDXW(2*(TL)+1)], acc); \
      acc = fmaf(F.f[7],  wv[IDXW(2*(TL)+2)], acc); \
      acc = fmaf(F.f[8],  wv[IDXW(2*(TL)+3)], acc); \
      acc = fmaf(F.f[9],  wv[IDXW(2*(TL)+4)], acc); \
      acc = fmaf(F.f[10], wv[IDXW(2*(TL)+5)], acc); \
      acc = fmaf(F.f[11], wv[IDXW(2*(TL)+6)], acc); \
      orow[(size_t)(t0 + (TL)) * CCH] = f2bf(acc); \
      if ((TL) < 31) { \
        float nv1 = su_val<2*(TL)+7>(xr, F, a, invb); \
        float nv2 = su_val<2*(TL)+8>(xr, F, a, invb); \
        if ((2*(TL)+7) > 63) nv1 = right ? su_hi : nv1; \
        if ((2*(TL)+8) > 63) nv2 = right ? su_hi : nv2; \
        wv[IDXW(2*(TL)+7)] = nv1; \
        wv[IDXW(2*(TL)+8)] = nv2; \
      } \
    }

    ACT_STEP(0)  ACT_STEP(1)  ACT_STEP(2)  ACT_STEP(3)
    ACT_STEP(4)  ACT_STEP(5)  ACT_STEP(6)  ACT_STEP(7)
    ACT_STEP(8)  ACT_STEP(9)  ACT_STEP(10) ACT_STEP(11)
    ACT_STEP(12) ACT_STEP(13) ACT_STEP(14) ACT_STEP(15)
    ACT_STEP(16) ACT_STEP(17) ACT_STEP(18) ACT_STEP(19)
    ACT_STEP(20) ACT_STEP(21) ACT_STEP(22) ACT_STEP(23)
    ACT_STEP(24) ACT_STEP(25) ACT_STEP(26) ACT_STEP(27)
    ACT_STEP(28) ACT_STEP(29) ACT_STEP(30) ACT_STEP(31)
#undef ACT_STEP
#undef IDXW
}

// ---------- wn_conv (k=3 dilated) as MFMA implicit GEMM + residual ----------
// A (weights) direct global->VGPR (contiguous 16B/lane, L1/L2-served, 2-way
// wave reuse + cross-block reuse). LDS holds only the X dbuf (2x12288B).
// ROUND-3 FIX: round 2's __launch_bounds__(256,4) capped arch regs at 128
// total -> acc went to AGPR, VGPR side starved at 64 -> scratch spill
// (WRITE_SIZE 68->227MB, MfmaUtil 12.6%). Natural allocation is ~128 VGPR
// with zero spill; at 128 VGPR the occupancy limit is 4 blocks/CU anyway
// (LDS limit is 6). So: plain __launch_bounds__(256), let the allocator
// pick, get 4 blocks/CU without spill.
__global__ __launch_bounds__(256) void k_conv(const u16* __restrict__ xt,
                                              const u16* __restrict__ wp,
                                              const float* __restrict__ scales,
                                              const void* __restrict__ bias,
                                              int bofs,
                                              const void* __restrict__ rsrc,
                                              int layer0,
                                              u16* __restrict__ wdst,
                                              void* __restrict__ outp, int d,
                                              const int* __restrict__ flg) {
    __shared__ __align__(16) char Xsm[2][12288];
    const int isf = *flg;
    const int rif = layer0 ? isf : 0;
    const int tid = threadIdx.x;
    const int lane = tid & 63, wid = tid >> 6;
    const int wm = wid & 1, wn = wid >> 1;
    const int b = blockIdx.z, co0 = blockIdx.y * 128, t0 = blockIdx.x * 128;
    const int q = lane >> 4, l15 = lane & 15;
    const int nX = (128 + 2 * d) * 4;              // live X granules
    const bool edge = (t0 == 0) || (t0 + 128 == TLEN);
    const u16* xtb = xt + (size_t)b * TLEN * CCH;

    // per-lane A base: row co0 + wm*64 + l15, k-offset q*8 (elements)
    // strides (elements): tap 262144, mi 8192, ci-step 32
    const u16* wbase = wp + ((size_t)(co0 + wm * 64 + l15)) * CCH + q * 8;

    // per-lane X staging source rows (step-invariant; ci0 added per step)
    const u16* xsrc3[3];
    #pragma unroll
    for (int i = 0; i < 3; ++i) {
        int L = (i * 4 + wid) * 64 + lane;
        int t = L >> 2;
        int g = (L & 3) ^ ((t >> 1) & 3);
        int tg = min(max(t0 - d + t, 0), TLEN - 1);
        xsrc3[i] = xtb + (size_t)tg * CCH + g * 8;
    }

    float4v acc[4][4];
    #pragma unroll
    for (int i = 0; i < 4; ++i)
        #pragma unroll
        for (int j = 0; j < 4; ++j) acc[i][j] = (float4v){0.f, 0.f, 0.f, 0.f};

    auto stageX = [&](int ci0, char* Xs) {
        #pragma unroll
        for (int i = 0; i < 3; ++i)
            gl_lds16(xsrc3[i] + ci0, Xs + (i * 4 + wid) * 64 * 16);
    };
    auto fixX = [&](char* Xs) {   // zero out-of-range rows (conv zero-pad)
        for (int j = tid; j < nX; j += 256) {
            int tg = t0 - d + (j >> 2);
            if (tg < 0 || tg >= TLEN)
                *(int4v*)(Xs + (size_t)j * 16) = (int4v){0, 0, 0, 0};
        }
    };

    // ---- prologue: stage step 0 ----
    stageX(0, Xsm[0]);
    __syncthreads();                       // vmcnt(0) drain + barrier
    if (edge) { fixX(Xsm[0]); __syncthreads(); }

    // ---- main loop: prefetch X(s+1) || A direct loads + MFMA on s ----
    #pragma unroll 2
    for (int s = 0; s < 16; ++s) {
        const int cur = s & 1;
        const char* Xs = Xsm[cur];
        if (s < 15) stageX((s + 1) * 32, Xsm[cur ^ 1]);
        #pragma unroll
        for (int tap = 0; tap < 3; ++tap) {
            short8 af[4], bfr[4];
            #pragma unroll
            for (int mi = 0; mi < 4; ++mi)
                af[mi] = *(const short8*)(wbase + (size_t)tap * 262144 +
                                          mi * 8192 + s * 32);
            #pragma unroll
            for (int ni = 0; ni < 4; ++ni) {
                int r = wn * 64 + ni * 16 + l15 + tap * d;
                bfr[ni] = *(const short8*)(Xs + r * 64 + ((q ^ ((r >> 1) & 3)) * 16));
            }
            #pragma unroll
            for (int mi = 0; mi < 4; ++mi)
                #pragma unroll
                for (int ni = 0; ni < 4; ++ni)
                    acc[mi][ni] = __builtin_amdgcn_mfma_f32_16x16x32_bf16(
                        af[mi], bfr[ni], acc[mi][ni], 0, 0, 0);
        }
        __syncthreads();                   // drains X prefetch + WAR guard
        if (edge && s < 15) {
            fixX(Xsm[cur ^ 1]);
            __syncthreads();
        }
    }

    // ---- epilogue: y = scale*acc + bias + residual ----
    float scl[4][4], bia[4][4];
    #pragma unroll
    for (int mi = 0; mi < 4; ++mi)
        #pragma unroll
        for (int rg = 0; rg < 4; ++rg) {
            int co = co0 + wm * 64 + mi * 16 + q * 4 + rg;
            scl[mi][rg] = scales[co];
            bia[mi][rg] = ldin(bias, bofs + co, isf);
        }
    #pragma unroll
    for (int mi = 0; mi < 4; ++mi)
        #pragma unroll
        for (int ni = 0; ni < 4; ++ni) {
            int tg = t0 + wn * 64 + ni * 16 + l15;
            #pragma unroll
            for (int rg = 0; rg < 4; ++rg) {
                int co = co0 + wm * 64 + mi * 16 + q * 4 + rg;
                size_t idx = ((size_t)(b * CCH + co)) * TLEN + tg;
                float resid = rif ? ((const float*)rsrc)[idx]
                                  : bf2f(((const u16*)rsrc)[idx]);
                float val = fmaf(acc[mi][ni][rg], scl[mi][rg], bia[mi][rg]) + resid;
                if (wdst) {
                    wdst[idx] = f2bf(val);
                } else {
                    if (isf) ((float*)outp)[idx] = val;
                    else ((u16*)outp)[idx] = f2bf(val);
                }
            }
        }
}

// ---------- launcher ----------
extern "C" void kernel_launch(void* const* d_in, const int* in_sizes, int n_in,
                              void* d_out, int out_size, void* d_ws, size_t ws_size,
                              hipStream_t stream) {
    const void* x_in  = d_in[0];
    const void* v_in  = d_in[1];
    const void* g_in  = d_in[2];
    const void* b_in  = d_in[3];
    const void* al_in = d_in[4];
    const void* be_in = d_in[5];

    char* ws = (char*)d_ws;
    u16*   xc     = (u16*)ws;                                     // 67108864 B
    u16*   xt     = (u16*)(ws + 67108864);                        // 67108864 B
    u16*   wp     = (u16*)(ws + 134217728);                       // 4718592 B
    float* scales = (float*)(ws + 134217728 + 4718592);           // 6144 B
    int*   flag   = (int*)(ws + 134217728 + 4718592 + 6144);

    Filt F;
    make_filter(F.f);

    k_detect<<<1, 256, 0, stream>>>((const u16*)x_in, flag);
    k_scales<<<3 * CCH, 256, 0, stream>>>(v_in, g_in, scales, flag);
    k_repack<<<dim3(3072, 3), 256, 0, stream>>>(v_in, wp, flag);

    const int dil[3] = {1, 3, 5};
    for (int l = 0; l < 3; ++l) {
        const void* src = (l == 0) ? x_in : (const void*)xc;
        k_act<<<dim3(TLEN / 128, CCH / 64, NB), 256, 0, stream>>>(
            src, al_in, be_in, l * CCH, xt, F, flag, (l == 0) ? 1 : 0);
        k_conv<<<dim3(TLEN / 128, CCH / 128, NB), 256, 0, stream>>>(
            xt, wp + (size_t)l * 3 * CCH * CCH, scales + l * CCH, b_in, l * CCH,
            src, (l == 0) ? 1 : 0,
            (l == 2) ? (u16*)nullptr : xc,
            (l == 2) ? d_out : nullptr, dil[l], flag);
    }
}

// Round 4
// 826.665 us; speedup vs baseline: 1.4535x; 1.3508x over previous
//
#include <hip/hip_runtime.h>
#include <hip/hip_bf16.h>
#include <cmath>

#define CCH 512
#define TLEN 8192
#define NB 8
#define KFILT 12

typedef unsigned short u16;
typedef __attribute__((ext_vector_type(8))) short short8;
typedef __attribute__((ext_vector_type(8))) unsigned short ushort8;
typedef __attribute__((ext_vector_type(4))) float float4v;
typedef __attribute__((ext_vector_type(4))) int int4v;

struct Filt { float f[KFILT]; };

// ---------- host: kaiser-sinc filter (double precision, matches numpy) ----------
static double bessel_i0(double x) {
    double sum = 1.0, term = 1.0;
    for (int k = 1; k < 40; ++k) {
        double t = (x * 0.5) / k;
        term *= t * t;
        sum += term;
        if (term < 1e-18 * sum) break;
    }
    return sum;
}

static void make_filter(float* out) {
    const int ksize = KFILT, half = KFILT / 2;
    const double cutoff = 0.5 / 2.0;
    const double half_width = 0.6 / 2.0;
    const double delta_f = 4.0 * half_width;
    const double PI = 3.14159265358979323846;
    double A = 2.285 * (half - 1) * PI * delta_f + 7.95;
    double beta;
    if (A > 50.0) beta = 0.1102 * (A - 8.7);
    else if (A >= 21.0) beta = 0.5842 * pow(A - 21.0, 0.4) + 0.07886 * (A - 21.0);
    else beta = 0.0;
    double i0b = bessel_i0(beta);
    double sum = 0.0, f[KFILT];
    for (int n = 0; n < ksize; ++n) {
        double r = (2.0 * n) / (ksize - 1) - 1.0;
        double w = bessel_i0(beta * sqrt(fmax(0.0, 1.0 - r * r))) / i0b;
        double t = (n - half) + 0.5;
        double xx = 2.0 * cutoff * t;
        double snc = (xx == 0.0) ? 1.0 : sin(PI * xx) / (PI * xx);
        f[n] = 2.0 * cutoff * w * snc;
        sum += f[n];
    }
    for (int n = 0; n < ksize; ++n) out[n] = (float)(f[n] / sum);
}

// ---------- device helpers ----------
__device__ __forceinline__ float bf2f(u16 u) {
    return __uint_as_float(((unsigned int)u) << 16);
}
__device__ __forceinline__ u16 f2bf(float f) {
    unsigned int x = __float_as_uint(f);
    unsigned int r = (x + 0x7fffu + ((x >> 16) & 1u)) >> 16;
    return (u16)r;
}
__device__ __forceinline__ float ldin(const void* p, size_t i, int isf) {
    return isf ? ((const float*)p)[i] : bf2f(((const u16*)p)[i]);
}
__device__ __forceinline__ void gl_lds16(const void* g, void* s) {
    __builtin_amdgcn_global_load_lds(
        (const __attribute__((address_space(1))) unsigned int*)g,
        (__attribute__((address_space(3))) unsigned int*)s, 16, 0, 0);
}

// ---------- dtype sniffer: bf16-view of f32 data has wild exponents ----------
__global__ __launch_bounds__(256) void k_detect(const u16* __restrict__ x,
                                                int* __restrict__ flag) {
    int tid = threadIdx.x;
    int bad = 0;
    for (int i = tid; i < 4096; i += 256) {
        int e = (x[i] >> 7) & 0xFF;
        if (e >= 0x86) bad++;   // |v| >= 64 or inf/nan as bf16
    }
    for (int off = 32; off > 0; off >>= 1) bad += __shfl_down(bad, off, 64);
    __shared__ int r[4];
    if ((tid & 63) == 0) r[tid >> 6] = bad;
    __syncthreads();
    if (tid == 0) flag[0] = (r[0] + r[1] + r[2] + r[3] >= 64) ? 1 : 0;
}

// ---------- per-out-channel weight-norm scale: g / ||v|| ----------
__global__ __launch_bounds__(256) void k_scales(const void* __restrict__ v,
                                                const void* __restrict__ g,
                                                float* __restrict__ scales,
                                                const int* __restrict__ flg) {
    int isf = *flg;
    int blk = blockIdx.x;            // [0, 3*512)
    int tid = threadIdx.x;
    float s = 0.f;
    for (int i = tid; i < CCH * 3; i += 256) {
        float x = ldin(v, (size_t)blk * (CCH * 3) + i, isf);
        s = fmaf(x, x, s);
    }
    for (int off = 32; off > 0; off >>= 1) s += __shfl_down(s, off, 64);
    __shared__ float red[4];
    if ((tid & 63) == 0) red[tid >> 6] = s;
    __syncthreads();
    if (tid == 0) {
        float tot = red[0] + red[1] + red[2] + red[3];
        scales[blk] = ldin(g, blk, isf) / sqrtf(tot);
    }
}

// ---------- repack weights: Wp[l][tap][co][ci] = v[l][co][ci][tap] (bf16) ----------
__global__ __launch_bounds__(256) void k_repack(const void* __restrict__ v,
                                                u16* __restrict__ wp,
                                                const int* __restrict__ flg) {
    int isf = *flg;
    int l = blockIdx.y;
    int i = blockIdx.x * 256 + threadIdx.x;   // < 3*512*512
    int tap = i >> 18;
    int rem = i & 262143;
    int co = rem >> 9, ci = rem & 511;
    size_t src = (((size_t)l * CCH + co) * CCH + ci) * 3 + tap;
    u16 val = isf ? f2bf(((const float*)v)[src]) : ((const u16*)v)[src];
    wp[(((size_t)l * 3 + tap) * CCH + co) * CCH + ci] = val;
}

// ---------- upsample+snake value generator, all indices compile-time ----------
template<int UL>
__device__ __forceinline__ float su_val(const float* xr, const Filt& F,
                                        float a, float invb) {
    constexpr int S = (UL < 0) ? -(((-UL) + 1) / 2) : (UL / 2);   // floor(UL/2)
    constexpr int P = ((UL % 2) + 2) % 2;                          // parity
    constexpr int B = S + (P ? 4 : 3);                             // xr base idx
    float acc = F.f[P] * xr[B];
    #pragma unroll
    for (int r = 1; r < 6; ++r) acc = fmaf(F.f[2 * r + P], xr[B + r], acc);
    acc *= 2.0f;
    float sn = __sinf(acc * a);
    return fmaf(invb, sn * sn, acc);
}

// ---------- fused activation1d: all-register streaming (zero LDS) ----------
__global__ __launch_bounds__(256) void k_act(const void* __restrict__ xsrc,
                                             const void* __restrict__ alpha,
                                             const void* __restrict__ beta,
                                             int prmofs, u16* __restrict__ xt,
                                             Filt F, const int* __restrict__ flg,
                                             int layer0) {
    const int isf = *flg;
    const int sif = layer0 ? isf : 0;   // carrier is always bf16 after layer 0
    const int tid = threadIdx.x;
    const int lane = tid & 63, w = tid >> 6;
    const int b = blockIdx.z;
    const int c = blockIdx.y * 64 + lane;
    const int t0 = blockIdx.x * 128 + w * 32;        // wave-uniform
    const size_t rowbase = ((size_t)(b * CCH + c)) * TLEN;

    const float a = expf(ldin(alpha, prmofs + c, isf));
    const float invb = 1.0f / (expf(ldin(beta, prmofs + c, isf)) + 1e-9f);

    // ---- x window: xr[k] = x[clamp(t0-6+k)], k in [0,44) ----
    float xr[44];
    const bool interior = (t0 != 0) && (t0 != TLEN - 32);   // wave-uniform
    if (sif) {
        const float* xp = (const float*)xsrc + rowbase;
        if (interior) {
            #pragma unroll
            for (int i = 0; i < 12; ++i) {
                float4v v = *(const float4v*)(xp + t0 - 8 + i * 4);
                #pragma unroll
                for (int j = 0; j < 4; ++j) {
                    int k = i * 4 + j - 2;
                    if (k >= 0 && k < 44) xr[k] = v[j];
                }
            }
        } else {
            #pragma unroll
            for (int k = 0; k < 44; ++k)
                xr[k] = xp[min(max(t0 - 6 + k, 0), TLEN - 1)];
        }
    } else {
        const u16* xp = (const u16*)xsrc + rowbase;
        if (interior) {
            #pragma unroll
            for (int i = 0; i < 6; ++i) {
                ushort8 v = *(const ushort8*)(xp + t0 - 8 + i * 8);
                #pragma unroll
                for (int j = 0; j < 8; ++j) {
                    int k = i * 8 + j - 2;
                    if (k >= 0 && k < 44) xr[k] = bf2f(v[j]);
                }
            }
        } else {
            #pragma unroll
            for (int k = 0; k < 44; ++k)
                xr[k] = bf2f(xp[min(max(t0 - 6 + k, 0), TLEN - 1)]);
        }
    }

    // ---- init rolling window: slots for u_local = -5..6, slot(u) = u mod 12 ----
    float wv[12];
    wv[7]  = su_val<-5>(xr, F, a, invb);
    wv[8]  = su_val<-4>(xr, F, a, invb);
    wv[9]  = su_val<-3>(xr, F, a, invb);
    wv[10] = su_val<-2>(xr, F, a, invb);
    wv[11] = su_val<-1>(xr, F, a, invb);
    wv[0]  = su_val<0>(xr, F, a, invb);
    wv[1]  = su_val<1>(xr, F, a, invb);
    wv[2]  = su_val<2>(xr, F, a, invb);
    wv[3]  = su_val<3>(xr, F, a, invb);
    wv[4]  = su_val<4>(xr, F, a, invb);
    wv[5]  = su_val<5>(xr, F, a, invb);
    wv[6]  = su_val<6>(xr, F, a, invb);
    // left edge: u<0 clamps to u=0 (edge-replicate of snake output)
    if (t0 == 0) { wv[7] = wv[8] = wv[9] = wv[10] = wv[11] = wv[0]; }
    // right edge: u>2T-1 clamps to u=2T-1 (odd, u_local=63 at the last thread)
    const bool right = (t0 == TLEN - 32);
    const float su_hi = su_val<63>(xr, F, a, invb);

    u16* orow = xt + (size_t)b * TLEN * CCH + c;

#define IDXW(u) ((((u) % 12) + 12) % 12)
#define ACT_STEP(TL) { \
      float acc = F.f[0] * wv[IDXW(2*(TL)-5)]; \
      acc = fmaf(F.f[1],  wv[IDXW(2*(TL)-4)], acc); \
      acc = fmaf(F.f[2],  wv[IDXW(2*(TL)-3)], acc); \
      acc = fmaf(F.f[3],  wv[IDXW(2*(TL)-2)], acc); \
      acc = fmaf(F.f[4],  wv[IDXW(2*(TL)-1)], acc); \
      acc = fmaf(F.f[5],  wv[IDXW(2*(TL)+0)], acc); \
      acc = fmaf(F.f[6],  wv[IDXW(2*(TL)+1)], acc); \
      acc = fmaf(F.f[7],  wv[IDXW(2*(TL)+2)], acc); \
      acc = fmaf(F.f[8],  wv[IDXW(2*(TL)+3)], acc); \
      acc = fmaf(F.f[9],  wv[IDXW(2*(TL)+4)], acc); \
      acc = fmaf(F.f[10], wv[IDXW(2*(TL)+5)], acc); \
      acc = fmaf(F.f[11], wv[IDXW(2*(TL)+6)], acc); \
      orow[(size_t)(t0 + (TL)) * CCH] = f2bf(acc); \
      if ((TL) < 31) { \
        float nv1 = su_val<2*(TL)+7>(xr, F, a, invb); \
        float nv2 = su_val<2*(TL)+8>(xr, F, a, invb); \
        if ((2*(TL)+7) > 63) nv1 = right ? su_hi : nv1; \
        if ((2*(TL)+8) > 63) nv2 = right ? su_hi : nv2; \
        wv[IDXW(2*(TL)+7)] = nv1; \
        wv[IDXW(2*(TL)+8)] = nv2; \
      } \
    }

    ACT_STEP(0)  ACT_STEP(1)  ACT_STEP(2)  ACT_STEP(3)
    ACT_STEP(4)  ACT_STEP(5)  ACT_STEP(6)  ACT_STEP(7)
    ACT_STEP(8)  ACT_STEP(9)  ACT_STEP(10) ACT_STEP(11)
    ACT_STEP(12) ACT_STEP(13) ACT_STEP(14) ACT_STEP(15)
    ACT_STEP(16) ACT_STEP(17) ACT_STEP(18) ACT_STEP(19)
    ACT_STEP(20) ACT_STEP(21) ACT_STEP(22) ACT_STEP(23)
    ACT_STEP(24) ACT_STEP(25) ACT_STEP(26) ACT_STEP(27)
    ACT_STEP(28) ACT_STEP(29) ACT_STEP(30) ACT_STEP(31)
#undef ACT_STEP
#undef IDXW
}

// ---------- wn_conv (k=3 dilated) as MFMA implicit GEMM + residual ----------
// Round-4: A back in LDS (round-3's A-direct regressed: VMEM latency on the
// per-step critical path). Structural fix per T3+T4 (counted vmcnt, never 0
// in main loop): TRIPLE-buffered A and X, prefetch distance 2, raw s_barrier
// (one per step) + s_waitcnt vmcnt(6). Per-wave vmcnt only orders a wave's
// own loads; the barrier makes it collective: each wave waits its own 6
// oldest (buffer s+1's) loads, then barrier => whole buffer landed.
// Edge-row zeroing is replaced by staging OOB lanes from a zeroed global
// scratch (zsrc), so there is no post-landing LDS fixup (which would race
// with in-flight gl_lds) and the step loop is uniform.
// 512 threads, tile 128co x 256t, 8 waves (2 co x 4 t), wave tile 64x64 --
// same per-wave register footprint as round 1 (~192 unified) = 2 waves/SIMD.
// LDS: 3 x (24576 A + 24576 X) = 147456 B dynamic -> 1 block/CU.
__global__ __launch_bounds__(512, 2) void k_conv(const u16* __restrict__ xt,
                                              const u16* __restrict__ wp,
                                              const float* __restrict__ scales,
                                              const void* __restrict__ bias,
                                              int bofs,
                                              const void* __restrict__ rsrc,
                                              int layer0,
                                              u16* __restrict__ wdst,
                                              void* __restrict__ outp, int d,
                                              const int* __restrict__ flg,
                                              const u16* __restrict__ zsrc) {
    extern __shared__ __align__(16) char smem[];
    const int isf = *flg;
    const int rif = layer0 ? isf : 0;
    const int tid = threadIdx.x;
    const int lane = tid & 63, wid = tid >> 6;
    const int wm = wid & 1, wn = wid >> 1;            // co half, t quarter
    const int b = blockIdx.z, co0 = blockIdx.y * 128, t0 = blockIdx.x * 256;
    const int q = lane >> 4, l15 = lane & 15;
    const u16* xtb = xt + (size_t)b * TLEN * CCH;

    // rotating buffer pointers (A stride 24576, X stride 24576)
    char* Ab[3] = { smem, smem + 24576, smem + 49152 };
    char* Xb[3] = { smem + 73728, smem + 98304, smem + 122880 };

    // ---- per-thread staging sources (step-invariant; +ci0 per step) ----
    // A: 1536 granules, 3 per thread. granule L: tap=L>>9, co=(L>>2)&127,
    //    g = (L&3) ^ ((co>>1)&3)  (XOR-swizzled 16B granules)
    const u16* wsrc3[3];
    #pragma unroll
    for (int i = 0; i < 3; ++i) {
        int L = i * 512 + tid;
        int tap = L >> 9;
        int co = (L >> 2) & 127;
        int g = (L & 3) ^ ((co >> 1) & 3);
        wsrc3[i] = wp + (((size_t)tap * CCH + co0 + co) * CCH) + g * 8;
    }
    // X: rows t0-d+t, t = idx>>2 in [0,384); OOB rows -> zeroed scratch
    const u16* xsrc3[3];
    #pragma unroll
    for (int i = 0; i < 3; ++i) {
        int idx = i * 512 + tid;
        int t = idx >> 2;
        int g = (idx & 3) ^ ((t >> 1) & 3);
        int tg = t0 - d + t;
        if (tg < 0 || tg >= TLEN) xsrc3[i] = zsrc;          // zeros
        else xsrc3[i] = xtb + (size_t)tg * CCH + g * 8;
    }

    auto stage = [&](int ci0, char* A, char* X) {
        #pragma unroll
        for (int i = 0; i < 3; ++i)
            gl_lds16(wsrc3[i] + ci0, A + (i * 512 + wid * 64) * 16);
        #pragma unroll
        for (int i = 0; i < 3; ++i)
            gl_lds16(xsrc3[i] + ci0, X + (i * 512 + wid * 64) * 16);
    };

    float4v acc[4][4];
    #pragma unroll
    for (int i = 0; i < 4; ++i)
        #pragma unroll
        for (int j = 0; j < 4; ++j) acc[i][j] = (float4v){0.f, 0.f, 0.f, 0.f};

    // ---- prologue: fill pipe to distance 2 ----
    stage(0, Ab[0], Xb[0]);     // 6 loads/thread
    stage(32, Ab[1], Xb[1]);    // 6 more -> 12 outstanding
    asm volatile("s_waitcnt vmcnt(6)" ::: "memory");   // buffer 0 landed
    __builtin_amdgcn_s_barrier();
    __builtin_amdgcn_sched_barrier(0);

    // ---- main loop: one raw barrier per step, vmcnt never 0 until tail ----
    char *Ac = Ab[0], *An = Ab[1], *Af = Ab[2];
    char *Xc = Xb[0], *Xn = Xb[1], *Xf = Xb[2];
    for (int s = 0; s < 16; ++s) {
        if (s < 14) stage((s + 2) * 32, Af, Xf);       // issue distance-2 loads
        #pragma unroll
        for (int tap = 0; tap < 3; ++tap) {
            short8 af[4], bfr[4];
            #pragma unroll
            for (int mi = 0; mi < 4; ++mi) {
                int co = wm * 64 + mi * 16 + l15;
                af[mi] = *(const short8*)(Ac + tap * 8192 + co * 64 +
                                          ((q ^ ((co >> 1) & 3)) * 16));
            }
            #pragma unroll
            for (int ni = 0; ni < 4; ++ni) {
                int r = wn * 64 + ni * 16 + l15 + tap * d;
                bfr[ni] = *(const short8*)(Xc + r * 64 + ((q ^ ((r >> 1) & 3)) * 16));
            }
            __builtin_amdgcn_s_setprio(1);
            #pragma unroll
            for (int mi = 0; mi < 4; ++mi)
                #pragma unroll
                for (int ni = 0; ni < 4; ++ni)
                    acc[mi][ni] = __builtin_amdgcn_mfma_f32_16x16x32_bf16(
                        af[mi], bfr[ni], acc[mi][ni], 0, 0, 0);
            __builtin_amdgcn_s_setprio(0);
        }
        if (s == 15) break;
        if (s < 14) asm volatile("s_waitcnt vmcnt(6)" ::: "memory");
        else        asm volatile("s_waitcnt vmcnt(0)" ::: "memory");
        __builtin_amdgcn_s_barrier();
        __builtin_amdgcn_sched_barrier(0);
        char* t1 = Ac; Ac = An; An = Af; Af = t1;
        char* t2 = Xc; Xc = Xn; Xn = Xf; Xf = t2;
    }

    // ---- epilogue: y = scale*acc + bias + residual ----
    float scl[4][4], bia[4][4];
    #pragma unroll
    for (int mi = 0; mi < 4; ++mi)
        #pragma unroll
        for (int rg = 0; rg < 4; ++rg) {
            int co = co0 + wm * 64 + mi * 16 + q * 4 + rg;
            scl[mi][rg] = scales[co];
            bia[mi][rg] = ldin(bias, bofs + co, isf);
        }
    #pragma unroll
    for (int mi = 0; mi < 4; ++mi)
        #pragma unroll
        for (int ni = 0; ni < 4; ++ni) {
            int tg = t0 + wn * 64 + ni * 16 + l15;
            #pragma unroll
            for (int rg = 0; rg < 4; ++rg) {
                int co = co0 + wm * 64 + mi * 16 + q * 4 + rg;
                size_t idx = ((size_t)(b * CCH + co)) * TLEN + tg;
                float resid = rif ? ((const float*)rsrc)[idx]
                                  : bf2f(((const u16*)rsrc)[idx]);
                float val = fmaf(acc[mi][ni][rg], scl[mi][rg], bia[mi][rg]) + resid;
                if (wdst) {
                    wdst[idx] = f2bf(val);
                } else {
                    if (isf) ((float*)outp)[idx] = val;
                    else ((u16*)outp)[idx] = f2bf(val);
                }
            }
        }
}

// ---------- launcher ----------
extern "C" void kernel_launch(void* const* d_in, const int* in_sizes, int n_in,
                              void* d_out, int out_size, void* d_ws, size_t ws_size,
                              hipStream_t stream) {
    const void* x_in  = d_in[0];
    const void* v_in  = d_in[1];
    const void* g_in  = d_in[2];
    const void* b_in  = d_in[3];
    const void* al_in = d_in[4];
    const void* be_in = d_in[5];

    char* ws = (char*)d_ws;
    u16*   xc     = (u16*)ws;                                     // 67108864 B
    u16*   xt     = (u16*)(ws + 67108864);                        // 67108864 B
    u16*   wp     = (u16*)(ws + 134217728);                       // 4718592 B
    float* scales = (float*)(ws + 134217728 + 4718592);           // 6144 B
    int*   flag   = (int*)(ws + 134217728 + 4718592 + 6144);      // 4 B
    u16*   zbuf   = (u16*)(ws + 134217728 + 4718592 + 6144 + 64); // 2048 B zeros

    Filt F;
    make_filter(F.f);

    // allow 147456 B dynamic LDS for k_conv (host-side attr, capture-safe)
    (void)hipFuncSetAttribute((const void*)k_conv,
                              hipFuncAttributeMaxDynamicSharedMemorySize, 147456);

    // zeroed staging source for out-of-range conv rows
    (void)hipMemsetAsync(zbuf, 0, 2048, stream);

    k_detect<<<1, 256, 0, stream>>>((const u16*)x_in, flag);
    k_scales<<<3 * CCH, 256, 0, stream>>>(v_in, g_in, scales, flag);
    k_repack<<<dim3(3072, 3), 256, 0, stream>>>(v_in, wp, flag);

    const int dil[3] = {1, 3, 5};
    for (int l = 0; l < 3; ++l) {
        const void* src = (l == 0) ? x_in : (const void*)xc;
        k_act<<<dim3(TLEN / 128, CCH / 64, NB), 256, 0, stream>>>(
            src, al_in, be_in, l * CCH, xt, F, flag, (l == 0) ? 1 : 0);
        k_conv<<<dim3(TLEN / 256, CCH / 128, NB), 512, 147456, stream>>>(
            xt, wp + (size_t)l * 3 * CCH * CCH, scales + l * CCH, b_in, l * CCH,
            src, (l == 0) ? 1 : 0,
            (l == 2) ? (u16*)nullptr : xc,
            (l == 2) ? d_out : nullptr, dil[l], flag, zbuf);
    }
}

// Round 5
// 757.587 us; speedup vs baseline: 1.5860x; 1.0912x over previous
//
#include <hip/hip_runtime.h>
#include <hip/hip_bf16.h>
#include <cmath>

#define CCH 512
#define TLEN 8192
#define NB 8
#define KFILT 12

typedef unsigned short u16;
typedef __attribute__((ext_vector_type(8))) short short8;
typedef __attribute__((ext_vector_type(8))) unsigned short ushort8;
typedef __attribute__((ext_vector_type(4))) float float4v;
typedef __attribute__((ext_vector_type(4))) int int4v;

struct Filt { float f[KFILT]; };

// ---------- host: kaiser-sinc filter (double precision, matches numpy) ----------
static double bessel_i0(double x) {
    double sum = 1.0, term = 1.0;
    for (int k = 1; k < 40; ++k) {
        double t = (x * 0.5) / k;
        term *= t * t;
        sum += term;
        if (term < 1e-18 * sum) break;
    }
    return sum;
}

static void make_filter(float* out) {
    const int ksize = KFILT, half = KFILT / 2;
    const double cutoff = 0.5 / 2.0;
    const double half_width = 0.6 / 2.0;
    const double delta_f = 4.0 * half_width;
    const double PI = 3.14159265358979323846;
    double A = 2.285 * (half - 1) * PI * delta_f + 7.95;
    double beta;
    if (A > 50.0) beta = 0.1102 * (A - 8.7);
    else if (A >= 21.0) beta = 0.5842 * pow(A - 21.0, 0.4) + 0.07886 * (A - 21.0);
    else beta = 0.0;
    double i0b = bessel_i0(beta);
    double sum = 0.0, f[KFILT];
    for (int n = 0; n < ksize; ++n) {
        double r = (2.0 * n) / (ksize - 1) - 1.0;
        double w = bessel_i0(beta * sqrt(fmax(0.0, 1.0 - r * r))) / i0b;
        double t = (n - half) + 0.5;
        double xx = 2.0 * cutoff * t;
        double snc = (xx == 0.0) ? 1.0 : sin(PI * xx) / (PI * xx);
        f[n] = 2.0 * cutoff * w * snc;
        sum += f[n];
    }
    for (int n = 0; n < ksize; ++n) out[n] = (float)(f[n] / sum);
}

// ---------- device helpers ----------
__device__ __forceinline__ float bf2f(u16 u) {
    return __uint_as_float(((unsigned int)u) << 16);
}
__device__ __forceinline__ u16 f2bf(float f) {
    unsigned int x = __float_as_uint(f);
    unsigned int r = (x + 0x7fffu + ((x >> 16) & 1u)) >> 16;
    return (u16)r;
}
__device__ __forceinline__ float ldin(const void* p, size_t i, int isf) {
    return isf ? ((const float*)p)[i] : bf2f(((const u16*)p)[i]);
}
__device__ __forceinline__ void gl_lds16(const void* g, void* s) {
    __builtin_amdgcn_global_load_lds(
        (const __attribute__((address_space(1))) unsigned int*)g,
        (__attribute__((address_space(3))) unsigned int*)s, 16, 0, 0);
}

// ---------- dtype sniffer: bf16-view of f32 data has wild exponents ----------
__global__ __launch_bounds__(256) void k_detect(const u16* __restrict__ x,
                                                int* __restrict__ flag) {
    int tid = threadIdx.x;
    int bad = 0;
    for (int i = tid; i < 4096; i += 256) {
        int e = (x[i] >> 7) & 0xFF;
        if (e >= 0x86) bad++;   // |v| >= 64 or inf/nan as bf16
    }
    for (int off = 32; off > 0; off >>= 1) bad += __shfl_down(bad, off, 64);
    __shared__ int r[4];
    if ((tid & 63) == 0) r[tid >> 6] = bad;
    __syncthreads();
    if (tid == 0) flag[0] = (r[0] + r[1] + r[2] + r[3] >= 64) ? 1 : 0;
}

// ---------- per-out-channel weight-norm scale: g / ||v|| ----------
__global__ __launch_bounds__(256) void k_scales(const void* __restrict__ v,
                                                const void* __restrict__ g,
                                                float* __restrict__ scales,
                                                const int* __restrict__ flg) {
    int isf = *flg;
    int blk = blockIdx.x;            // [0, 3*512)
    int tid = threadIdx.x;
    float s = 0.f;
    for (int i = tid; i < CCH * 3; i += 256) {
        float x = ldin(v, (size_t)blk * (CCH * 3) + i, isf);
        s = fmaf(x, x, s);
    }
    for (int off = 32; off > 0; off >>= 1) s += __shfl_down(s, off, 64);
    __shared__ float red[4];
    if ((tid & 63) == 0) red[tid >> 6] = s;
    __syncthreads();
    if (tid == 0) {
        float tot = red[0] + red[1] + red[2] + red[3];
        scales[blk] = ldin(g, blk, isf) / sqrtf(tot);
    }
}

// ---------- repack weights: Wp[l][tap][co][ci] = v[l][co][ci][tap] (bf16) ----------
__global__ __launch_bounds__(256) void k_repack(const void* __restrict__ v,
                                                u16* __restrict__ wp,
                                                const int* __restrict__ flg) {
    int isf = *flg;
    int l = blockIdx.y;
    int i = blockIdx.x * 256 + threadIdx.x;   // < 3*512*512
    int tap = i >> 18;
    int rem = i & 262143;
    int co = rem >> 9, ci = rem & 511;
    size_t src = (((size_t)l * CCH + co) * CCH + ci) * 3 + tap;
    u16 val = isf ? f2bf(((const float*)v)[src]) : ((const u16*)v)[src];
    wp[(((size_t)l * 3 + tap) * CCH + co) * CCH + ci] = val;
}

// ---------- upsample+snake value generator, all indices compile-time ----------
template<int UL>
__device__ __forceinline__ float su_val(const float* xr, const Filt& F,
                                        float a, float invb) {
    constexpr int S = (UL < 0) ? -(((-UL) + 1) / 2) : (UL / 2);   // floor(UL/2)
    constexpr int P = ((UL % 2) + 2) % 2;                          // parity
    constexpr int B = S + (P ? 4 : 3);                             // xr base idx
    float acc = F.f[P] * xr[B];
    #pragma unroll
    for (int r = 1; r < 6; ++r) acc = fmaf(F.f[2 * r + P], xr[B + r], acc);
    acc *= 2.0f;
    float sn = __sinf(acc * a);
    return fmaf(invb, sn * sn, acc);
}

// ---------- fused activation1d: all-register streaming (zero LDS) ----------
__global__ __launch_bounds__(256) void k_act(const void* __restrict__ xsrc,
                                             const void* __restrict__ alpha,
                                             const void* __restrict__ beta,
                                             int prmofs, u16* __restrict__ xt,
                                             Filt F, const int* __restrict__ flg,
                                             int layer0) {
    const int isf = *flg;
    const int sif = layer0 ? isf : 0;   // carrier is always bf16 after layer 0
    const int tid = threadIdx.x;
    const int lane = tid & 63, w = tid >> 6;
    const int b = blockIdx.z;
    const int c = blockIdx.y * 64 + lane;
    const int t0 = blockIdx.x * 128 + w * 32;        // wave-uniform
    const size_t rowbase = ((size_t)(b * CCH + c)) * TLEN;

    const float a = expf(ldin(alpha, prmofs + c, isf));
    const float invb = 1.0f / (expf(ldin(beta, prmofs + c, isf)) + 1e-9f);

    // ---- x window: xr[k] = x[clamp(t0-6+k)], k in [0,44) ----
    float xr[44];
    const bool interior = (t0 != 0) && (t0 != TLEN - 32);   // wave-uniform
    if (sif) {
        const float* xp = (const float*)xsrc + rowbase;
        if (interior) {
            #pragma unroll
            for (int i = 0; i < 12; ++i) {
                float4v v = *(const float4v*)(xp + t0 - 8 + i * 4);
                #pragma unroll
                for (int j = 0; j < 4; ++j) {
                    int k = i * 4 + j - 2;
                    if (k >= 0 && k < 44) xr[k] = v[j];
                }
            }
        } else {
            #pragma unroll
            for (int k = 0; k < 44; ++k)
                xr[k] = xp[min(max(t0 - 6 + k, 0), TLEN - 1)];
        }
    } else {
        const u16* xp = (const u16*)xsrc + rowbase;
        if (interior) {
            #pragma unroll
            for (int i = 0; i < 6; ++i) {
                ushort8 v = *(const ushort8*)(xp + t0 - 8 + i * 8);
                #pragma unroll
                for (int j = 0; j < 8; ++j) {
                    int k = i * 8 + j - 2;
                    if (k >= 0 && k < 44) xr[k] = bf2f(v[j]);
                }
            }
        } else {
            #pragma unroll
            for (int k = 0; k < 44; ++k)
                xr[k] = bf2f(xp[min(max(t0 - 6 + k, 0), TLEN - 1)]);
        }
    }

    // ---- init rolling window: slots for u_local = -5..6, slot(u) = u mod 12 ----
    float wv[12];
    wv[7]  = su_val<-5>(xr, F, a, invb);
    wv[8]  = su_val<-4>(xr, F, a, invb);
    wv[9]  = su_val<-3>(xr, F, a, invb);
    wv[10] = su_val<-2>(xr, F, a, invb);
    wv[11] = su_val<-1>(xr, F, a, invb);
    wv[0]  = su_val<0>(xr, F, a, invb);
    wv[1]  = su_val<1>(xr, F, a, invb);
    wv[2]  = su_val<2>(xr, F, a, invb);
    wv[3]  = su_val<3>(xr, F, a, invb);
    wv[4]  = su_val<4>(xr, F, a, invb);
    wv[5]  = su_val<5>(xr, F, a, invb);
    wv[6]  = su_val<6>(xr, F, a, invb);
    // left edge: u<0 clamps to u=0 (edge-replicate of snake output)
    if (t0 == 0) { wv[7] = wv[8] = wv[9] = wv[10] = wv[11] = wv[0]; }
    // right edge: u>2T-1 clamps to u=2T-1 (odd, u_local=63 at the last thread)
    const bool right = (t0 == TLEN - 32);
    const float su_hi = su_val<63>(xr, F, a, invb);

    u16* orow = xt + (size_t)b * TLEN * CCH + c;

#define IDXW(u) ((((u) % 12) + 12) % 12)
#define ACT_STEP(TL) { \
      float acc = F.f[0] * wv[IDXW(2*(TL)-5)]; \
      acc = fmaf(F.f[1],  wv[IDXW(2*(TL)-4)], acc); \
      acc = fmaf(F.f[2],  wv[IDXW(2*(TL)-3)], acc); \
      acc = fmaf(F.f[3],  wv[IDXW(2*(TL)-2)], acc); \
      acc = fmaf(F.f[4],  wv[IDXW(2*(TL)-1)], acc); \
      acc = fmaf(F.f[5],  wv[IDXW(2*(TL)+0)], acc); \
      acc = fmaf(F.f[6],  wv[IDXW(2*(TL)+1)], acc); \
      acc = fmaf(F.f[7],  wv[IDXW(2*(TL)+2)], acc); \
      acc = fmaf(F.f[8],  wv[IDXW(2*(TL)+3)], acc); \
      acc = fmaf(F.f[9],  wv[IDXW(2*(TL)+4)], acc); \
      acc = fmaf(F.f[10], wv[IDXW(2*(TL)+5)], acc); \
      acc = fmaf(F.f[11], wv[IDXW(2*(TL)+6)], acc); \
      orow[(size_t)(t0 + (TL)) * CCH] = f2bf(acc); \
      if ((TL) < 31) { \
        float nv1 = su_val<2*(TL)+7>(xr, F, a, invb); \
        float nv2 = su_val<2*(TL)+8>(xr, F, a, invb); \
        if ((2*(TL)+7) > 63) nv1 = right ? su_hi : nv1; \
        if ((2*(TL)+8) > 63) nv2 = right ? su_hi : nv2; \
        wv[IDXW(2*(TL)+7)] = nv1; \
        wv[IDXW(2*(TL)+8)] = nv2; \
      } \
    }

    ACT_STEP(0)  ACT_STEP(1)  ACT_STEP(2)  ACT_STEP(3)
    ACT_STEP(4)  ACT_STEP(5)  ACT_STEP(6)  ACT_STEP(7)
    ACT_STEP(8)  ACT_STEP(9)  ACT_STEP(10) ACT_STEP(11)
    ACT_STEP(12) ACT_STEP(13) ACT_STEP(14) ACT_STEP(15)
    ACT_STEP(16) ACT_STEP(17) ACT_STEP(18) ACT_STEP(19)
    ACT_STEP(20) ACT_STEP(21) ACT_STEP(22) ACT_STEP(23)
    ACT_STEP(24) ACT_STEP(25) ACT_STEP(26) ACT_STEP(27)
    ACT_STEP(28) ACT_STEP(29) ACT_STEP(30) ACT_STEP(31)
#undef ACT_STEP
#undef IDXW
}

// ---------- wn_conv (k=3 dilated) as MFMA implicit GEMM + residual ----------
// Round-5: TLP fix. Three schedule variants (r0/r1/r4) all plateaued at
// ~185us / MfmaUtil 23% with 8 waves/CU (2/SIMD) — the invariant is
// residency, not the sync scheme. This version halves the per-wave acc
// (wave tile 64co x 32t -> 32 AGPR) so a wave fits well under 128 unified
// regs; __launch_bounds__(512,4) caps at 128 (round-4 body fit exactly 128
// WITH a 64-AGPR acc, so 32-AGPR body has ~32 regs of slack -> no spill).
// LDS: A dbuf 2x24576 + X dbuf 2x9216 (144 rows, trimmed from r4's 384)
// = 67584 B -> 2 blocks/CU. Result: 16 waves/CU = 4/SIMD, and the two
// co-resident blocks hit barriers at independent phases (m97's overlap
// mechanism). Sync: simple proven 2-phase __syncthreads; OOB rows staged
// from zeroed scratch (zsrc) so no LDS fixup is needed.
__global__ __launch_bounds__(512, 4) void k_conv(const u16* __restrict__ xt,
                                              const u16* __restrict__ wp,
                                              const float* __restrict__ scales,
                                              const void* __restrict__ bias,
                                              int bofs,
                                              const void* __restrict__ rsrc,
                                              int layer0,
                                              u16* __restrict__ wdst,
                                              void* __restrict__ outp, int d,
                                              const int* __restrict__ flg,
                                              const u16* __restrict__ zsrc) {
    extern __shared__ __align__(16) char smem[];
    // layout: A0 [0,24576) A1 [24576,49152) X0 [49152,58368) X1 [58368,67584)
    const int isf = *flg;
    const int rif = layer0 ? isf : 0;
    const int tid = threadIdx.x;
    const int lane = tid & 63, wid = tid >> 6;
    const int wm = wid & 1, wn = wid >> 1;          // co half (64), t quarter (32)
    const int b = blockIdx.z, co0 = blockIdx.y * 128, t0 = blockIdx.x * 128;
    const int q = lane >> 4, l15 = lane & 15;
    const u16* xtb = xt + (size_t)b * TLEN * CCH;

    // ---- A staging sources: 1536 granules, 3/thread (XOR-swizzled source) ----
    const u16* wsrc3[3];
    #pragma unroll
    for (int i = 0; i < 3; ++i) {
        int L = i * 512 + tid;
        int tap = L >> 9;
        int co = (L >> 2) & 127;
        int g = (L & 3) ^ ((co >> 1) & 3);
        wsrc3[i] = wp + (((size_t)tap * CCH + co0 + co) * CCH) + g * 8;
    }
    // ---- X staging: 576 granules = 144 rows (need 128+2d<=138); OOB -> zsrc ----
    const u16* xsrc0;
    const u16* xsrc1 = zsrc;
    {
        int t = tid >> 2;
        int g = (tid & 3) ^ ((t >> 1) & 3);
        int tg = t0 - d + t;
        xsrc0 = (tg < 0 || tg >= TLEN) ? zsrc : xtb + (size_t)tg * CCH + g * 8;
    }
    if (tid < 64) {
        int j = 512 + tid;
        int t = j >> 2;
        int g = (j & 3) ^ ((t >> 1) & 3);
        int tg = t0 - d + t;
        xsrc1 = (tg < 0 || tg >= TLEN) ? zsrc : xtb + (size_t)tg * CCH + g * 8;
    }

    auto stage = [&](int ci0, char* A, char* X) {
        #pragma unroll
        for (int i = 0; i < 3; ++i)
            gl_lds16(wsrc3[i] + ci0, A + (i * 512 + wid * 64) * 16);
        gl_lds16(xsrc0 + ci0, X + wid * 1024);
        if (tid < 64) gl_lds16(xsrc1 + ci0, X + 8192);
    };

    float4v acc[4][2];
    #pragma unroll
    for (int i = 0; i < 4; ++i)
        #pragma unroll
        for (int j = 0; j < 2; ++j) acc[i][j] = (float4v){0.f, 0.f, 0.f, 0.f};

    // ---- prologue ----
    stage(0, smem, smem + 49152);
    __syncthreads();

    // ---- main loop: 2-phase dbuf, one barrier per step ----
    for (int s = 0; s < 16; ++s) {
        char* Ac = smem + (s & 1) * 24576;
        char* Xc = smem + 49152 + (s & 1) * 9216;
        if (s < 15) {
            char* An = smem + ((s + 1) & 1) * 24576;
            char* Xn = smem + 49152 + ((s + 1) & 1) * 9216;
            stage((s + 1) * 32, An, Xn);
        }
        #pragma unroll
        for (int tap = 0; tap < 3; ++tap) {
            short8 af[4], bfr[2];
            #pragma unroll
            for (int mi = 0; mi < 4; ++mi) {
                int co = wm * 64 + mi * 16 + l15;
                af[mi] = *(const short8*)(Ac + tap * 8192 + co * 64 +
                                          ((q ^ ((co >> 1) & 3)) * 16));
            }
            #pragma unroll
            for (int ni = 0; ni < 2; ++ni) {
                int r = wn * 32 + ni * 16 + l15 + tap * d;
                bfr[ni] = *(const short8*)(Xc + r * 64 + ((q ^ ((r >> 1) & 3)) * 16));
            }
            __builtin_amdgcn_s_setprio(1);
            #pragma unroll
            for (int mi = 0; mi < 4; ++mi)
                #pragma unroll
                for (int ni = 0; ni < 2; ++ni)
                    acc[mi][ni] = __builtin_amdgcn_mfma_f32_16x16x32_bf16(
                        af[mi], bfr[ni], acc[mi][ni], 0, 0, 0);
            __builtin_amdgcn_s_setprio(0);
        }
        __syncthreads();   // drains prefetch; WAR guard for next stage
    }

    // ---- epilogue: y = scale*acc + bias + residual ----
    float scl[4][4], bia[4][4];
    #pragma unroll
    for (int mi = 0; mi < 4; ++mi)
        #pragma unroll
        for (int rg = 0; rg < 4; ++rg) {
            int co = co0 + wm * 64 + mi * 16 + q * 4 + rg;
            scl[mi][rg] = scales[co];
            bia[mi][rg] = ldin(bias, bofs + co, isf);
        }
    #pragma unroll
    for (int mi = 0; mi < 4; ++mi)
        #pragma unroll
        for (int ni = 0; ni < 2; ++ni) {
            int tg = t0 + wn * 32 + ni * 16 + l15;
            #pragma unroll
            for (int rg = 0; rg < 4; ++rg) {
                int co = co0 + wm * 64 + mi * 16 + q * 4 + rg;
                size_t idx = ((size_t)(b * CCH + co)) * TLEN + tg;
                float resid = rif ? ((const float*)rsrc)[idx]
                                  : bf2f(((const u16*)rsrc)[idx]);
                float val = fmaf(acc[mi][ni][rg], scl[mi][rg], bia[mi][rg]) + resid;
                if (wdst) {
                    wdst[idx] = f2bf(val);
                } else {
                    if (isf) ((float*)outp)[idx] = val;
                    else ((u16*)outp)[idx] = f2bf(val);
                }
            }
        }
}

// ---------- launcher ----------
extern "C" void kernel_launch(void* const* d_in, const int* in_sizes, int n_in,
                              void* d_out, int out_size, void* d_ws, size_t ws_size,
                              hipStream_t stream) {
    const void* x_in  = d_in[0];
    const void* v_in  = d_in[1];
    const void* g_in  = d_in[2];
    const void* b_in  = d_in[3];
    const void* al_in = d_in[4];
    const void* be_in = d_in[5];

    char* ws = (char*)d_ws;
    u16*   xc     = (u16*)ws;                                     // 67108864 B
    u16*   xt     = (u16*)(ws + 67108864);                        // 67108864 B
    u16*   wp     = (u16*)(ws + 134217728);                       // 4718592 B
    float* scales = (float*)(ws + 134217728 + 4718592);           // 6144 B
    int*   flag   = (int*)(ws + 134217728 + 4718592 + 6144);      // 4 B
    u16*   zbuf   = (u16*)(ws + 134217728 + 4718592 + 6144 + 64); // 2048 B zeros

    Filt F;
    make_filter(F.f);

    // allow 67584 B dynamic LDS for k_conv (host-side attr, capture-safe)
    (void)hipFuncSetAttribute((const void*)k_conv,
                              hipFuncAttributeMaxDynamicSharedMemorySize, 67584);

    // zeroed staging source for out-of-range conv rows
    (void)hipMemsetAsync(zbuf, 0, 2048, stream);

    k_detect<<<1, 256, 0, stream>>>((const u16*)x_in, flag);
    k_scales<<<3 * CCH, 256, 0, stream>>>(v_in, g_in, scales, flag);
    k_repack<<<dim3(3072, 3), 256, 0, stream>>>(v_in, wp, flag);

    const int dil[3] = {1, 3, 5};
    for (int l = 0; l < 3; ++l) {
        const void* src = (l == 0) ? x_in : (const void*)xc;
        k_act<<<dim3(TLEN / 128, CCH / 64, NB), 256, 0, stream>>>(
            src, al_in, be_in, l * CCH, xt, F, flag, (l == 0) ? 1 : 0);
        k_conv<<<dim3(TLEN / 128, CCH / 128, NB), 512, 67584, stream>>>(
            xt, wp + (size_t)l * 3 * CCH * CCH, scales + l * CCH, b_in, l * CCH,
            src, (l == 0) ? 1 : 0,
            (l == 2) ? (u16*)nullptr : xc,
            (l == 2) ? d_out : nullptr, dil[l], flag, zbuf);
    }
}